// Round 6
// baseline (564.007 us; speedup 1.0000x reference)
//
#include <hip/hip_runtime.h>
#include <stdint.h>

#define P_DIM 256
#define NREF  4096
#define NIN   8192
#define DF    512
#define NE    4
#define CREF  1536              // per-element capacity (ref rows)   [mean 1024]
#define CIN   2560              // per-element capacity (query rows) [mean 2048]
#define AE_LD (NE * CREF)       // Ae row stride = 6144

// ---- R6 MEASUREMENT PROBE (revert next round) ----
// g1 repeats its whole body 8x, g2 16x, idempotently. Purpose: (a) their
// dispatches exceed the 43us poison fills and surface in top-5 WITH counters
// (MfmaUtil/FETCH/occupancy); (b) dur_us = base + 7*T1 + 15*T2 disambiguates
// even if only one shows. Everything else byte-identical to R5.
#define G1_REP 8
#define G2_REP 16

typedef __bf16 bf16x8 __attribute__((ext_vector_type(8)));
typedef float  f32x4  __attribute__((ext_vector_type(4)));
typedef unsigned short ush8 __attribute__((ext_vector_type(8)));

static __device__ __forceinline__ unsigned short f2bf(float f) {
    uint32_t u = __builtin_bit_cast(uint32_t, f);
    u += 0x7FFFu + ((u >> 16) & 1u);
    return (unsigned short)(u >> 16);
}

// Single-block stable counting sort: builds iperm (slot->src row for X_ref),
// jperm (slot->src row for desc), cnt[8]. No global atomics.
// ORDER LESSON (R1/R2): thread t owns the CONTIGUOUS row range [t*CH,(t+1)*CH)
// so each bucket stays nearly sorted ascending -> downstream gathers stream
// X_ref/desc/Alpha almost sequentially (a strided assignment cost ~8us).
__global__ __launch_bounds__(256) void plan_sort(
    const int* __restrict__ Zr, const int* __restrict__ Z,
    int* __restrict__ iperm, int* __restrict__ jperm, int* __restrict__ cnt) {
    const int t = threadIdx.x;
    const int lane = t & 63, wv = t >> 6;
    constexpr int CHX = NREF / 256;   // 16
    constexpr int CHD = NIN / 256;    // 32

    __shared__ int wpart[2][NE][4];   // [X/D][bucket][wave] inclusive totals

    int zx[CHX], zd[CHD];
    int cx[NE], cd[NE];
#pragma unroll
    for (int e = 0; e < NE; ++e) { cx[e] = 0; cd[e] = 0; }
#pragma unroll
    for (int k = 0; k < CHX; ++k) {
        zx[k] = Zr[t * CHX + k] & (NE - 1);
#pragma unroll
        for (int e = 0; e < NE; ++e) cx[e] += (zx[k] == e);
    }
#pragma unroll
    for (int k = 0; k < CHD; ++k) {
        zd[k] = Z[t * CHD + k] & (NE - 1);
#pragma unroll
        for (int e = 0; e < NE; ++e) cd[e] += (zd[k] == e);
    }

    int sx[NE], sd[NE];
#pragma unroll
    for (int e = 0; e < NE; ++e) { sx[e] = cx[e]; sd[e] = cd[e]; }
#pragma unroll
    for (int d = 1; d < 64; d <<= 1) {
#pragma unroll
        for (int e = 0; e < NE; ++e) {
            int ux = __shfl_up(sx[e], d, 64);
            int ud = __shfl_up(sd[e], d, 64);
            if (lane >= d) { sx[e] += ux; sd[e] += ud; }
        }
    }
    if (lane == 63) {
#pragma unroll
        for (int e = 0; e < NE; ++e) { wpart[0][e][wv] = sx[e]; wpart[1][e][wv] = sd[e]; }
    }
    __syncthreads();

#pragma unroll
    for (int e = 0; e < NE; ++e) {
        int ox = 0, od = 0;
#pragma unroll
        for (int w2 = 0; w2 < 4; ++w2) {
            if (w2 < wv) { ox += wpart[0][e][w2]; od += wpart[1][e][w2]; }
        }
        sx[e] += ox - cx[e];
        sd[e] += od - cd[e];
    }

    if (t < 2 * NE) {
        int b = t & (NE - 1);
        int isD = t >> 2;
        cnt[t] = wpart[isD][b][0] + wpart[isD][b][1]
               + wpart[isD][b][2] + wpart[isD][b][3];
    }

#pragma unroll
    for (int k = 0; k < CHX; ++k) {
        int i = t * CHX + k;
#pragma unroll
        for (int e = 0; e < NE; ++e)
            if (zx[k] == e) { iperm[e * CREF + sx[e]] = i; sx[e]++; }
    }
#pragma unroll
    for (int k = 0; k < CHD; ++k) {
        int j = t * CHD + k;
#pragma unroll
        for (int e = 0; e < NE; ++e)
            if (zd[k] == e) { jperm[e * CIN + sd[e]] = j; sd[e]++; }
    }
}

#define GATHER_BLOCKS (NE * (CREF + CIN) / 4)      // 4096 blocks of 4 waves
#define ALPHA_BLOCKS  (P_DIM * AE_LD / (256 * 8))  // 768 blocks, 8 cols/thread

__global__ void gather_all(const float* __restrict__ Alpha,
                           const float* __restrict__ X_ref, const float* __restrict__ desc,
                           const int* __restrict__ iperm, const int* __restrict__ jperm,
                           const int* __restrict__ cnt,
                           unsigned short* __restrict__ Xe, unsigned short* __restrict__ De,
                           unsigned short* __restrict__ Ae) {
    if (blockIdx.x < GATHER_BLOCKS) {
        int w = (blockIdx.x * blockDim.x + threadIdx.x) >> 6;
        int lane = threadIdx.x & 63;
        const float* src = nullptr;
        unsigned short* dstp;
        if (w < NE * CREF) {
            int e = w / CREF, s = w - e * CREF;
            if (s < cnt[e]) src = X_ref + (size_t)iperm[w] * DF;
            dstp = Xe + (size_t)w * DF;
        } else {
            int w2 = w - NE * CREF;
            int e = w2 / CIN, s = w2 - e * CIN;
            if (s < cnt[NE + e]) src = desc + (size_t)jperm[w2] * DF;
            dstp = De + (size_t)w2 * DF;
        }
        ush8 o;
        if (src) {
            float4 a = *(const float4*)(src + lane * 8);
            float4 b = *(const float4*)(src + lane * 8 + 4);
            o[0] = f2bf(a.x); o[1] = f2bf(a.y); o[2] = f2bf(a.z); o[3] = f2bf(a.w);
            o[4] = f2bf(b.x); o[5] = f2bf(b.y); o[6] = f2bf(b.z); o[7] = f2bf(b.w);
        } else {
            o = (ush8){0, 0, 0, 0, 0, 0, 0, 0};
        }
        *(ush8*)(dstp + lane * 8) = o;
    } else {
        int idx8 = (blockIdx.x - GATHER_BLOCKS) * 256 + threadIdx.x;
        int p = idx8 / (AE_LD / 8);
        int c8 = idx8 - p * (AE_LD / 8);
        int col0 = c8 * 8;
        int e = col0 / CREF;
        int ic0 = col0 - e * CREF;
        int cn = cnt[e];
        const int* ip = iperm + col0;
        ush8 v;
#pragma unroll
        for (int k = 0; k < 8; ++k) {
            unsigned short r = 0;
            if (ic0 + k < cn) r = f2bf(Alpha[(size_t)p * NREF + ip[k]]);
            v[k] = r;
        }
        *(ush8*)(Ae + (size_t)idx8 * 8) = v;
    }
}

// Per-element GEMM1: Kt_e[jl, il] = (De_jl . Xe_il)^2  (bf16, row stride CREF).
// R6 PROBE: body repeated G1_REP times idempotently (same C rewritten).
__global__ __launch_bounds__(256) void g1_grouped(
    const unsigned short* __restrict__ DeA, const unsigned short* __restrict__ XeA,
    unsigned short* __restrict__ KtA, const int* __restrict__ cnt) {
    constexpr int BK = 64;
    const int e = blockIdx.z;
    const int padR = (cnt[e] + 127) & ~127;
    const int padI = (cnt[NE + e] + 127) & ~127;
    const int m0 = blockIdx.y * 128;   // jl (query rows)
    const int n0 = blockIdx.x * 128;   // il (ref rows)
    if (m0 >= padI || n0 >= padR) return;

    const unsigned short* A = DeA + (size_t)e * CIN * DF;
    const unsigned short* B = XeA + (size_t)e * CREF * DF;
    unsigned short* C = KtA + (size_t)e * CIN * CREF;

    __shared__ unsigned short tA[128 * BK];
    __shared__ unsigned short tB[128 * BK];

    const int tid = threadIdx.x, wave = tid >> 6, lane = tid & 63;
    const int wr = wave >> 1, wc = wave & 1;
    const int waveM = wr * 64, waveN = wc * 64;
    const int lrow = lane >> 3, ls = lane & 7;
    const int l15 = lane & 15, lq = lane >> 4;

#pragma unroll 1
    for (int rep = 0; rep < G1_REP; ++rep) {
        f32x4 acc[4][4];
#pragma unroll
        for (int r = 0; r < 4; ++r)
#pragma unroll
            for (int c = 0; c < 4; ++c) acc[r][c] = (f32x4){0.f, 0.f, 0.f, 0.f};

#pragma unroll 1
        for (int k0 = 0; k0 < DF; k0 += BK) {
            __syncthreads();
#pragma unroll
            for (int it = 0; it < 8; ++it) {
                int cb = wave + it * 4;
                bool isB = cb >= 16;
                int cb2 = isB ? cb - 16 : cb;
                int row = cb2 * 8 + lrow;
                int g = ls ^ (row & 7);
                const unsigned short* gp = (isB ? B : A)
                    + (size_t)((isB ? n0 : m0) + row) * DF + (size_t)(k0 + g * 8);
                unsigned short* lp = (isB ? tB : tA) + cb2 * (8 * BK);
                __builtin_amdgcn_global_load_lds(
                    (const __attribute__((address_space(1))) void*)gp,
                    (__attribute__((address_space(3))) void*)lp, 16, 0, 0);
            }
            __syncthreads();
#pragma unroll
            for (int kk = 0; kk < BK; kk += 32) {
                const int cbase = kk >> 3;
                bf16x8 af[4], bfr[4];
#pragma unroll
                for (int r = 0; r < 4; ++r) {
                    int m = waveM + r * 16 + l15;
                    int ch = (cbase + lq) ^ (m & 7);
                    af[r] = *(const bf16x8*)&tA[m * BK + ch * 8];
                }
#pragma unroll
                for (int c = 0; c < 4; ++c) {
                    int n = waveN + c * 16 + l15;
                    int ch = (cbase + lq) ^ (n & 7);
                    bfr[c] = *(const bf16x8*)&tB[n * BK + ch * 8];
                }
#pragma unroll
                for (int r = 0; r < 4; ++r)
#pragma unroll
                    for (int c = 0; c < 4; ++c)
                        acc[r][c] = __builtin_amdgcn_mfma_f32_16x16x32_bf16(
                            af[r], bfr[c], acc[r][c], 0, 0, 0);
            }
        }

#pragma unroll
        for (int r = 0; r < 4; ++r) {
            int mb = m0 + waveM + r * 16 + lq * 4;
#pragma unroll
            for (int reg = 0; reg < 4; ++reg) {
                size_t ro = (size_t)(mb + reg) * CREF;
#pragma unroll
                for (int c = 0; c < 4; ++c) {
                    int n = n0 + waveN + c * 16 + l15;
                    float v = acc[r][c][reg];
                    C[ro + n] = f2bf(v * v);
                }
            }
        }
        __syncthreads();   // rep boundary: C-writes are global, LDS reuse is safe after this
    }
}

// Per-element GEMM2 + scatter: out[p, jperm[jl]] = sum_il Ae[p,il] * Kt_e[jl,il].
// R6 PROBE: body repeated G2_REP times idempotently (same out rewritten).
__global__ __launch_bounds__(256) void g2_grouped(
    const unsigned short* __restrict__ Ae, const unsigned short* __restrict__ KtA,
    const int* __restrict__ jperm, const int* __restrict__ cnt,
    float* __restrict__ out) {
    constexpr int BK = 64;
    const int e = blockIdx.z;
    const int cntI = cnt[NE + e];
    const int padR = (cnt[e] + 127) & ~127;
    const int n0 = blockIdx.x * 64;    // jl
    const int m0 = blockIdx.y * 128;   // p
    if (n0 >= cntI) return;

    const unsigned short* B = KtA + (size_t)e * CIN * CREF;

    __shared__ unsigned short tA[2][128 * BK];
    __shared__ unsigned short tB[2][64 * BK];

    const int tid = threadIdx.x, wave = tid >> 6, lane = tid & 63;
    const int wr = wave >> 1, wc = wave & 1;
    const int waveM = wr * 64, waveN = wc * 32;
    const int lrow = lane >> 3, ls = lane & 7;
    const int l15 = lane & 15, lq = lane >> 4;

    auto stage = [&](int buf, int k0) {
#pragma unroll
        for (int it = 0; it < 6; ++it) {
            int cb = wave + it * 4;
            bool isB = cb >= 16;
            int cb2 = isB ? cb - 16 : cb;
            int row = cb2 * 8 + lrow;
            int g = ls ^ (row & 7);
            const unsigned short* gp = isB
                ? B + (size_t)(n0 + row) * CREF + (size_t)(k0 + g * 8)
                : Ae + (size_t)(m0 + row) * AE_LD + (size_t)(e * CREF + k0 + g * 8);
            unsigned short* lp = (isB ? tB[buf] : tA[buf]) + cb2 * (8 * BK);
            __builtin_amdgcn_global_load_lds(
                (const __attribute__((address_space(1))) void*)gp,
                (__attribute__((address_space(3))) void*)lp, 16, 0, 0);
        }
    };

#pragma unroll 1
    for (int rep = 0; rep < G2_REP; ++rep) {
        f32x4 acc[4][2];
#pragma unroll
        for (int r = 0; r < 4; ++r)
#pragma unroll
            for (int c = 0; c < 2; ++c) acc[r][c] = (f32x4){0.f, 0.f, 0.f, 0.f};

        if (padR > 0) {
            stage(0, 0);
            __syncthreads();
            int buf = 0;
#pragma unroll 1
            for (int k0 = 0; k0 < padR; k0 += BK) {
                if (k0 + BK < padR) stage(buf ^ 1, k0 + BK);
#pragma unroll
                for (int kk = 0; kk < BK; kk += 32) {
                    const int cbase = kk >> 3;
                    bf16x8 af[4], bfr[2];
#pragma unroll
                    for (int r = 0; r < 4; ++r) {
                        int m = waveM + r * 16 + l15;
                        int ch = (cbase + lq) ^ (m & 7);
                        af[r] = *(const bf16x8*)&tA[buf][m * BK + ch * 8];
                    }
#pragma unroll
                    for (int c = 0; c < 2; ++c) {
                        int n = waveN + c * 16 + l15;
                        int ch = (cbase + lq) ^ (n & 7);
                        bfr[c] = *(const bf16x8*)&tB[buf][n * BK + ch * 8];
                    }
#pragma unroll
                    for (int r = 0; r < 4; ++r)
#pragma unroll
                        for (int c = 0; c < 2; ++c)
                            acc[r][c] = __builtin_amdgcn_mfma_f32_16x16x32_bf16(
                                af[r], bfr[c], acc[r][c], 0, 0, 0);
                }
                __syncthreads();
                buf ^= 1;
            }
        }

        int jok[2], jdest[2];
#pragma unroll
        for (int c = 0; c < 2; ++c) {
            int jl = n0 + waveN + c * 16 + l15;
            jok[c] = jl < cntI;
            jdest[c] = jok[c] ? jperm[e * CIN + jl] : 0;
        }
#pragma unroll
        for (int r = 0; r < 4; ++r) {
            int pb = m0 + waveM + r * 16 + lq * 4;
#pragma unroll
            for (int reg = 0; reg < 4; ++reg) {
                size_t ro = (size_t)(pb + reg) * NIN;
#pragma unroll
                for (int c = 0; c < 2; ++c)
                    if (jok[c]) out[ro + jdest[c]] = acc[r][c][reg];
            }
        }
    }
}

extern "C" void kernel_launch(void* const* d_in, const int* in_sizes, int n_in,
                              void* d_out, int out_size, void* d_ws, size_t ws_size,
                              hipStream_t stream) {
    const float* Alpha = (const float*)d_in[0];   // [256, 4096]
    const float* X_ref = (const float*)d_in[1];   // [4096, 512]
    const float* desc  = (const float*)d_in[2];   // [8192, 512]
    const int*   Z_ref = (const int*)d_in[3];     // [4096]
    const int*   Z     = (const int*)d_in[4];     // [8192]
    float* out = (float*)d_out;                   // [256, 8192]

    // ws (ushort units): Xe 6.3MB | De 10.5MB | Ae 3.1MB | Kt 31.5MB | perms/cnt
    unsigned short* Xe = (unsigned short*)d_ws;            // NE*CREF*DF
    unsigned short* De = Xe + (size_t)NE * CREF * DF;      // NE*CIN*DF
    unsigned short* Ae = De + (size_t)NE * CIN * DF;       // P_DIM*AE_LD
    unsigned short* Kt = Ae + (size_t)P_DIM * AE_LD;       // NE*CIN*CREF
    int* iperm = (int*)(Kt + (size_t)NE * CIN * CREF);     // NE*CREF
    int* jperm = iperm + NE * CREF;                        // NE*CIN
    int* cnt   = jperm + NE * CIN;                         // 8

    plan_sort<<<1, 256, 0, stream>>>(Z_ref, Z, iperm, jperm, cnt);

    gather_all<<<GATHER_BLOCKS + ALPHA_BLOCKS, 256, 0, stream>>>(
        Alpha, X_ref, desc, iperm, jperm, cnt, Xe, De, Ae);

    g1_grouped<<<dim3(CREF / 128, CIN / 128, NE), 256, 0, stream>>>(De, Xe, Kt, cnt);

    g2_grouped<<<dim3(CIN / 64, P_DIM / 128, NE), 256, 0, stream>>>(Ae, Kt, jperm, cnt, out);
}

// Round 7
// 296.843 us; speedup vs baseline: 1.9000x; 1.9000x over previous
//
#include <hip/hip_runtime.h>
#include <stdint.h>

#define P_DIM 256
#define NREF  4096
#define NIN   8192
#define DF    512
#define NE    4
#define CREF  1536              // per-element capacity (ref rows)   [mean 1024]
#define CIN   2560              // per-element capacity (query rows) [mean 2048]
#define AE_LD (NE * CREF)       // Ae row stride = 6144

// ---- R7 PROBES (revert next round) ----
// gather_all x8 and (new) g2 x8, idempotent, with per-rep memory clobbers.
// Purpose: surface both in top-5 with counters. T1 (g1) already known: 18.9us.
#define GA_REP 8
#define G2_REP 8

typedef __bf16 bf16x8 __attribute__((ext_vector_type(8)));
typedef float  f32x4  __attribute__((ext_vector_type(4)));
typedef unsigned short ush8 __attribute__((ext_vector_type(8)));

static __device__ __forceinline__ unsigned short f2bf(float f) {
    uint32_t u = __builtin_bit_cast(uint32_t, f);
    u += 0x7FFFu + ((u >> 16) & 1u);
    return (unsigned short)(u >> 16);
}

// Single-block stable counting sort (R5 wave-parallel scan; measured-neutral
// vs serial but kept). ORDER LESSON (R1/R2): thread t owns CONTIGUOUS rows
// [t*CH,(t+1)*CH) so buckets stay nearly-sorted -> downstream gathers stream.
__global__ __launch_bounds__(256) void plan_sort(
    const int* __restrict__ Zr, const int* __restrict__ Z,
    int* __restrict__ iperm, int* __restrict__ jperm, int* __restrict__ cnt) {
    const int t = threadIdx.x;
    const int lane = t & 63, wv = t >> 6;
    constexpr int CHX = NREF / 256;   // 16
    constexpr int CHD = NIN / 256;    // 32

    __shared__ int wpart[2][NE][4];

    int zx[CHX], zd[CHD];
    int cx[NE], cd[NE];
#pragma unroll
    for (int e = 0; e < NE; ++e) { cx[e] = 0; cd[e] = 0; }
#pragma unroll
    for (int k = 0; k < CHX; ++k) {
        zx[k] = Zr[t * CHX + k] & (NE - 1);
#pragma unroll
        for (int e = 0; e < NE; ++e) cx[e] += (zx[k] == e);
    }
#pragma unroll
    for (int k = 0; k < CHD; ++k) {
        zd[k] = Z[t * CHD + k] & (NE - 1);
#pragma unroll
        for (int e = 0; e < NE; ++e) cd[e] += (zd[k] == e);
    }

    int sx[NE], sd[NE];
#pragma unroll
    for (int e = 0; e < NE; ++e) { sx[e] = cx[e]; sd[e] = cd[e]; }
#pragma unroll
    for (int d = 1; d < 64; d <<= 1) {
#pragma unroll
        for (int e = 0; e < NE; ++e) {
            int ux = __shfl_up(sx[e], d, 64);
            int ud = __shfl_up(sd[e], d, 64);
            if (lane >= d) { sx[e] += ux; sd[e] += ud; }
        }
    }
    if (lane == 63) {
#pragma unroll
        for (int e = 0; e < NE; ++e) { wpart[0][e][wv] = sx[e]; wpart[1][e][wv] = sd[e]; }
    }
    __syncthreads();

#pragma unroll
    for (int e = 0; e < NE; ++e) {
        int ox = 0, od = 0;
#pragma unroll
        for (int w2 = 0; w2 < 4; ++w2) {
            if (w2 < wv) { ox += wpart[0][e][w2]; od += wpart[1][e][w2]; }
        }
        sx[e] += ox - cx[e];
        sd[e] += od - cd[e];
    }

    if (t < 2 * NE) {
        int b = t & (NE - 1);
        int isD = t >> 2;
        cnt[t] = wpart[isD][b][0] + wpart[isD][b][1]
               + wpart[isD][b][2] + wpart[isD][b][3];
    }

#pragma unroll
    for (int k = 0; k < CHX; ++k) {
        int i = t * CHX + k;
#pragma unroll
        for (int e = 0; e < NE; ++e)
            if (zx[k] == e) { iperm[e * CREF + sx[e]] = i; sx[e]++; }
    }
#pragma unroll
    for (int k = 0; k < CHD; ++k) {
        int j = t * CHD + k;
#pragma unroll
        for (int e = 0; e < NE; ++e)
            if (zd[k] == e) { jperm[e * CIN + sd[e]] = j; sd[e]++; }
    }
}

#define GATHER_BLOCKS (NE * (CREF + CIN) / 4)      // 4096 blocks of 4 waves
#define ALPHA_BLOCKS  (P_DIM * AE_LD / (256 * 8))  // 768 blocks, 8 cols/thread

// Fused gather. R7 PROBE: whole body repeated GA_REP times; memory clobber per
// rep prevents load-hoisting / store-elision (rule #17 analog).
__global__ void gather_all(const float* __restrict__ Alpha,
                           const float* __restrict__ X_ref, const float* __restrict__ desc,
                           const int* __restrict__ iperm, const int* __restrict__ jperm,
                           const int* __restrict__ cnt,
                           unsigned short* __restrict__ Xe, unsigned short* __restrict__ De,
                           unsigned short* __restrict__ Ae) {
#pragma unroll 1
    for (int rep = 0; rep < GA_REP; ++rep) {
        asm volatile("" ::: "memory");
        if (blockIdx.x < GATHER_BLOCKS) {
            int w = (blockIdx.x * blockDim.x + threadIdx.x) >> 6;
            int lane = threadIdx.x & 63;
            const float* src = nullptr;
            unsigned short* dstp;
            if (w < NE * CREF) {
                int e = w / CREF, s = w - e * CREF;
                if (s < cnt[e]) src = X_ref + (size_t)iperm[w] * DF;
                dstp = Xe + (size_t)w * DF;
            } else {
                int w2 = w - NE * CREF;
                int e = w2 / CIN, s = w2 - e * CIN;
                if (s < cnt[NE + e]) src = desc + (size_t)jperm[w2] * DF;
                dstp = De + (size_t)w2 * DF;
            }
            ush8 o;
            if (src) {
                float4 a = *(const float4*)(src + lane * 8);
                float4 b = *(const float4*)(src + lane * 8 + 4);
                o[0] = f2bf(a.x); o[1] = f2bf(a.y); o[2] = f2bf(a.z); o[3] = f2bf(a.w);
                o[4] = f2bf(b.x); o[5] = f2bf(b.y); o[6] = f2bf(b.z); o[7] = f2bf(b.w);
            } else {
                o = (ush8){0, 0, 0, 0, 0, 0, 0, 0};
            }
            *(ush8*)(dstp + lane * 8) = o;
        } else {
            int idx8 = (blockIdx.x - GATHER_BLOCKS) * 256 + threadIdx.x;
            int p = idx8 / (AE_LD / 8);
            int c8 = idx8 - p * (AE_LD / 8);
            int col0 = c8 * 8;
            int e = col0 / CREF;
            int ic0 = col0 - e * CREF;
            int cn = cnt[e];
            const int* ip = iperm + col0;
            ush8 v;
#pragma unroll
            for (int k = 0; k < 8; ++k) {
                unsigned short r = 0;
                if (ic0 + k < cn) r = f2bf(Alpha[(size_t)p * NREF + ip[k]]);
                v[k] = r;
            }
            *(ush8*)(Ae + (size_t)idx8 * 8) = v;
        }
    }
}

// Per-element GEMM1: Kt_e[jl, il] = (De_jl . Xe_il)^2. Unchanged (T1=18.9us).
__global__ __launch_bounds__(256) void g1_grouped(
    const unsigned short* __restrict__ DeA, const unsigned short* __restrict__ XeA,
    unsigned short* __restrict__ KtA, const int* __restrict__ cnt) {
    constexpr int BK = 64;
    const int e = blockIdx.z;
    const int padR = (cnt[e] + 127) & ~127;
    const int padI = (cnt[NE + e] + 127) & ~127;
    const int m0 = blockIdx.y * 128;   // jl (query rows)
    const int n0 = blockIdx.x * 128;   // il (ref rows)
    if (m0 >= padI || n0 >= padR) return;

    const unsigned short* A = DeA + (size_t)e * CIN * DF;
    const unsigned short* B = XeA + (size_t)e * CREF * DF;
    unsigned short* C = KtA + (size_t)e * CIN * CREF;

    __shared__ unsigned short tA[128 * BK];
    __shared__ unsigned short tB[128 * BK];

    const int tid = threadIdx.x, wave = tid >> 6, lane = tid & 63;
    const int wr = wave >> 1, wc = wave & 1;
    const int waveM = wr * 64, waveN = wc * 64;
    const int lrow = lane >> 3, ls = lane & 7;
    const int l15 = lane & 15, lq = lane >> 4;

    f32x4 acc[4][4];
#pragma unroll
    for (int r = 0; r < 4; ++r)
#pragma unroll
        for (int c = 0; c < 4; ++c) acc[r][c] = (f32x4){0.f, 0.f, 0.f, 0.f};

#pragma unroll 1
    for (int k0 = 0; k0 < DF; k0 += BK) {
        __syncthreads();
#pragma unroll
        for (int it = 0; it < 8; ++it) {
            int cb = wave + it * 4;
            bool isB = cb >= 16;
            int cb2 = isB ? cb - 16 : cb;
            int row = cb2 * 8 + lrow;
            int g = ls ^ (row & 7);
            const unsigned short* gp = (isB ? B : A)
                + (size_t)((isB ? n0 : m0) + row) * DF + (size_t)(k0 + g * 8);
            unsigned short* lp = (isB ? tB : tA) + cb2 * (8 * BK);
            __builtin_amdgcn_global_load_lds(
                (const __attribute__((address_space(1))) void*)gp,
                (__attribute__((address_space(3))) void*)lp, 16, 0, 0);
        }
        __syncthreads();
#pragma unroll
        for (int kk = 0; kk < BK; kk += 32) {
            const int cbase = kk >> 3;
            bf16x8 af[4], bfr[4];
#pragma unroll
            for (int r = 0; r < 4; ++r) {
                int m = waveM + r * 16 + l15;
                int ch = (cbase + lq) ^ (m & 7);
                af[r] = *(const bf16x8*)&tA[m * BK + ch * 8];
            }
#pragma unroll
            for (int c = 0; c < 4; ++c) {
                int n = waveN + c * 16 + l15;
                int ch = (cbase + lq) ^ (n & 7);
                bfr[c] = *(const bf16x8*)&tB[n * BK + ch * 8];
            }
#pragma unroll
            for (int r = 0; r < 4; ++r)
#pragma unroll
                for (int c = 0; c < 4; ++c)
                    acc[r][c] = __builtin_amdgcn_mfma_f32_16x16x32_bf16(
                        af[r], bfr[c], acc[r][c], 0, 0, 0);
        }
    }

#pragma unroll
    for (int r = 0; r < 4; ++r) {
        int mb = m0 + waveM + r * 16 + lq * 4;
#pragma unroll
        for (int reg = 0; reg < 4; ++reg) {
            size_t ro = (size_t)(mb + reg) * CREF;
#pragma unroll
            for (int c = 0; c < 4; ++c) {
                int n = n0 + waveN + c * 16 + l15;
                float v = acc[r][c][reg];
                C[ro + n] = f2bf(v * v);
            }
        }
    }
}

// Per-element GEMM2 + scatter. R7 RESTRUCTURE: p-tile 64 (was 128), 4 waves of
// 32x32, LDS 32KB -> 512 real blocks = 2/CU (was 256 = 1/CU, Occupancy 10.6%,
// latency-bound at 18.8us vs ~7us HBM floor). Same K-accumulation order ->
// bit-identical output. R7 PROBE: body repeated G2_REP times idempotently.
__global__ __launch_bounds__(256) void g2_grouped(
    const unsigned short* __restrict__ Ae, const unsigned short* __restrict__ KtA,
    const int* __restrict__ jperm, const int* __restrict__ cnt,
    float* __restrict__ out) {
    constexpr int BK = 64;
    const int e = blockIdx.z;
    const int cntI = cnt[NE + e];
    const int padR = (cnt[e] + 127) & ~127;
    const int n0 = blockIdx.x * 64;    // jl
    const int m0 = blockIdx.y * 64;    // p
    if (n0 >= cntI) return;

    const unsigned short* B = KtA + (size_t)e * CIN * CREF;

    __shared__ unsigned short tA[2][64 * BK];
    __shared__ unsigned short tB[2][64 * BK];

    const int tid = threadIdx.x, wave = tid >> 6, lane = tid & 63;
    const int wr = wave >> 1, wc = wave & 1;
    const int waveM = wr * 32, waveN = wc * 32;
    const int lrow = lane >> 3, ls = lane & 7;
    const int l15 = lane & 15, lq = lane >> 4;

    auto stage = [&](int buf, int k0) {
#pragma unroll
        for (int it = 0; it < 4; ++it) {
            int cb = wave + it * 4;        // 0..15
            bool isB = cb >= 8;
            int cb2 = isB ? cb - 8 : cb;   // 0..7 chunks of 8 rows
            int row = cb2 * 8 + lrow;
            int g = ls ^ (row & 7);
            const unsigned short* gp = isB
                ? B + (size_t)(n0 + row) * CREF + (size_t)(k0 + g * 8)
                : Ae + (size_t)(m0 + row) * AE_LD + (size_t)(e * CREF + k0 + g * 8);
            unsigned short* lp = (isB ? tB[buf] : tA[buf]) + cb2 * (8 * BK);
            __builtin_amdgcn_global_load_lds(
                (const __attribute__((address_space(1))) void*)gp,
                (__attribute__((address_space(3))) void*)lp, 16, 0, 0);
        }
    };

#pragma unroll 1
    for (int rep = 0; rep < G2_REP; ++rep) {
        asm volatile("" ::: "memory");
        f32x4 acc[2][2];
#pragma unroll
        for (int r = 0; r < 2; ++r)
#pragma unroll
            for (int c = 0; c < 2; ++c) acc[r][c] = (f32x4){0.f, 0.f, 0.f, 0.f};

        stage(0, 0);
        __syncthreads();
        int buf = 0;
#pragma unroll 1
        for (int k0 = 0; k0 < padR; k0 += BK) {
            if (k0 + BK < padR) stage(buf ^ 1, k0 + BK);
#pragma unroll
            for (int kk = 0; kk < BK; kk += 32) {
                const int cbase = kk >> 3;
                bf16x8 af[2], bfr[2];
#pragma unroll
                for (int r = 0; r < 2; ++r) {
                    int m = waveM + r * 16 + l15;
                    int ch = (cbase + lq) ^ (m & 7);
                    af[r] = *(const bf16x8*)&tA[buf][m * BK + ch * 8];
                }
#pragma unroll
                for (int c = 0; c < 2; ++c) {
                    int n = waveN + c * 16 + l15;
                    int ch = (cbase + lq) ^ (n & 7);
                    bfr[c] = *(const bf16x8*)&tB[buf][n * BK + ch * 8];
                }
#pragma unroll
                for (int r = 0; r < 2; ++r)
#pragma unroll
                    for (int c = 0; c < 2; ++c)
                        acc[r][c] = __builtin_amdgcn_mfma_f32_16x16x32_bf16(
                            af[r], bfr[c], acc[r][c], 0, 0, 0);
            }
            __syncthreads();
            buf ^= 1;
        }

        int jok[2], jdest[2];
#pragma unroll
        for (int c = 0; c < 2; ++c) {
            int jl = n0 + waveN + c * 16 + l15;
            jok[c] = jl < cntI;
            jdest[c] = jok[c] ? jperm[e * CIN + jl] : 0;
        }
#pragma unroll
        for (int r = 0; r < 2; ++r) {
            int pb = m0 + waveM + r * 16 + lq * 4;
#pragma unroll
            for (int reg = 0; reg < 4; ++reg) {
                size_t ro = (size_t)(pb + reg) * NIN;
#pragma unroll
                for (int c = 0; c < 2; ++c)
                    if (jok[c]) out[ro + jdest[c]] = acc[r][c][reg];
            }
        }
    }
}

extern "C" void kernel_launch(void* const* d_in, const int* in_sizes, int n_in,
                              void* d_out, int out_size, void* d_ws, size_t ws_size,
                              hipStream_t stream) {
    const float* Alpha = (const float*)d_in[0];   // [256, 4096]
    const float* X_ref = (const float*)d_in[1];   // [4096, 512]
    const float* desc  = (const float*)d_in[2];   // [8192, 512]
    const int*   Z_ref = (const int*)d_in[3];     // [4096]
    const int*   Z     = (const int*)d_in[4];     // [8192]
    float* out = (float*)d_out;                   // [256, 8192]

    // ws (ushort units): Xe 6.3MB | De 10.5MB | Ae 3.1MB | Kt 31.5MB | perms/cnt
    unsigned short* Xe = (unsigned short*)d_ws;            // NE*CREF*DF
    unsigned short* De = Xe + (size_t)NE * CREF * DF;      // NE*CIN*DF
    unsigned short* Ae = De + (size_t)NE * CIN * DF;       // P_DIM*AE_LD
    unsigned short* Kt = Ae + (size_t)P_DIM * AE_LD;       // NE*CIN*CREF
    int* iperm = (int*)(Kt + (size_t)NE * CIN * CREF);     // NE*CREF
    int* jperm = iperm + NE * CREF;                        // NE*CIN
    int* cnt   = jperm + NE * CIN;                         // 8

    plan_sort<<<1, 256, 0, stream>>>(Z_ref, Z, iperm, jperm, cnt);

    gather_all<<<GATHER_BLOCKS + ALPHA_BLOCKS, 256, 0, stream>>>(
        Alpha, X_ref, desc, iperm, jperm, cnt, Xe, De, Ae);

    g1_grouped<<<dim3(CREF / 128, CIN / 128, NE), 256, 0, stream>>>(De, Xe, Kt, cnt);

    g2_grouped<<<dim3(CIN / 64, P_DIM / 64, NE), 256, 0, stream>>>(Ae, Kt, jperm, cnt, out);
}